// Round 9
// baseline (326.078 us; speedup 1.0000x reference)
//
#include <hip/hip_runtime.h>
#include <cstdint>
#include <cstddef>

typedef __attribute__((ext_vector_type(8))) short short8;
typedef __attribute__((ext_vector_type(4))) float f32x4;

#define QSCALE 0.18033688011112043f  // 0.125 * log2(e)

__device__ __forceinline__ float bf2f(unsigned short u) {
  return __uint_as_float(((unsigned)u) << 16);
}
__device__ __forceinline__ unsigned short f2bf(float f) {
  unsigned u = __float_as_uint(f);
  u += 0x7fffu + ((u >> 16) & 1u);
  return (unsigned short)(u >> 16);
}
// pack two f32 -> 2 bf16 (RNE) in one VALU op: lo=a, hi=b
__device__ __forceinline__ unsigned cvtpk(float a, float b) {
  unsigned r;
  asm("v_cvt_pk_bf16_f32 %0, %1, %2" : "=v"(r) : "v"(a), "v"(b));
  return r;
}
__device__ __forceinline__ short8 mk8(unsigned a, unsigned b, unsigned c, unsigned d) {
  union { unsigned u[4]; short8 s; } x;
  x.u[0] = a; x.u[1] = b; x.u[2] = c; x.u[3] = d;
  return x.s;
}
__device__ __forceinline__ void g2l16(const void* g, void* l) {
  __builtin_amdgcn_global_load_lds(
      (const __attribute__((address_space(1))) unsigned int*)g,
      (__attribute__((address_space(3))) unsigned int*)l, 16, 0, 0);
}

// ---------------- fused: weight conversion + GroupNorm partial sums ----------------
// blocks [0,1024): f32->bf16 weight convert; blocks [1024,2048): GN partial sums.
__global__ __launch_bounds__(256) void k_wgn(const float* __restrict__ wqf,
                                             const float* __restrict__ wpf,
                                             unsigned short* __restrict__ wq,
                                             unsigned short* __restrict__ wp,
                                             const float* __restrict__ x,
                                             float* __restrict__ part) {
  __shared__ float red[8];
  const int blk = blockIdx.x;
  const int t = threadIdx.x;
  if (blk < 1024) {
    int i = blk * 256 + t;
    if (i < 196608) {
      float4 v = ((const float4*)wqf)[i];
      ushort4 u;
      u.x = f2bf(v.x); u.y = f2bf(v.y); u.z = f2bf(v.z); u.w = f2bf(v.w);
      ((ushort4*)wq)[i] = u;
    } else {
      int k = i - 196608;
      float4 v = ((const float4*)wpf)[k];
      ushort4 u;
      u.x = f2bf(v.x); u.y = f2bf(v.y); u.z = f2bf(v.z); u.w = f2bf(v.w);
      ((ushort4*)wp)[k] = u;
    }
  } else {
    int b2 = blk - 1024;
    int bg = b2 >> 4, slice = b2 & 15;
    const float4* base = (const float4*)(x + (size_t)bg * 65536 + (size_t)slice * 4096);
    float s = 0.f, q = 0.f;
#pragma unroll
    for (int i = 0; i < 4; ++i) {
      float4 v = base[t + i * 256];
      s += v.x + v.y + v.z + v.w;
      q += v.x * v.x + v.y * v.y + v.z * v.z + v.w * v.w;
    }
#pragma unroll
    for (int off = 1; off < 64; off <<= 1) {
      s += __shfl_xor(s, off);
      q += __shfl_xor(q, off);
    }
    int wid = t >> 6;
    if ((t & 63) == 0) { red[wid * 2] = s; red[wid * 2 + 1] = q; }
    __syncthreads();
    if (t == 0) {
      float S = red[0] + red[2] + red[4] + red[6];
      float Q = red[1] + red[3] + red[5] + red[7];
      part[b2 * 2] = S;
      part[b2 * 2 + 1] = Q;
    }
  }
}

// ---------------- GroupNorm normalize: xn + xnT (stats fused in) ----------------
// Each block reduces the 16 partials for its own 4 groups (replaces k_gnfin).
__global__ __launch_bounds__(256) void k_gnnorm(const float* __restrict__ x,
                                                const float* __restrict__ gnw,
                                                const float* __restrict__ gnb,
                                                const float* __restrict__ part,
                                                unsigned short* __restrict__ xn,
                                                unsigned short* __restrict__ xnT) {
  __shared__ float T[64 * 65];
  __shared__ float sstats[8];  // 4 groups x (mean, rstd)
  const int t = threadIdx.x;
  const int n0 = blockIdx.x * 64, c0 = blockIdx.y * 64, bb = blockIdx.z;
  if (t < 4) {
    int gg = bb * 32 + (c0 >> 4) + t;
    float S = 0.f, Q = 0.f;
#pragma unroll
    for (int i = 0; i < 16; ++i) {
      S += part[(gg * 16 + i) * 2];
      Q += part[(gg * 16 + i) * 2 + 1];
    }
    float mean = S * (1.f / 65536.f);
    float var = Q * (1.f / 65536.f) - mean * mean;
    sstats[t * 2] = mean;
    sstats[t * 2 + 1] = rsqrtf(var + 1e-6f);
  }
  __syncthreads();
#pragma unroll
  for (int p = 0; p < 4; ++p) {
    int s = p * 256 + t;
    int row = s >> 4, seg = s & 15;
    int c = c0 + row;
    float mean = sstats[(row >> 4) * 2], rstd = sstats[(row >> 4) * 2 + 1];
    float gw = gnw[c] * rstd;
    float gb = gnb[c] - mean * gw;
    float4 v = *(const float4*)(x + ((size_t)bb * 512 + c) * 4096 + n0 + seg * 4);
    float f0 = v.x * gw + gb, f1 = v.y * gw + gb, f2 = v.z * gw + gb, f3 = v.w * gw + gb;
    ushort4 u;
    u.x = f2bf(f0); u.y = f2bf(f1); u.z = f2bf(f2); u.w = f2bf(f3);
    *(ushort4*)(xn + ((size_t)bb * 512 + c) * 4096 + n0 + seg * 4) = u;
    T[(seg * 4 + 0) * 65 + row] = f0;
    T[(seg * 4 + 1) * 65 + row] = f1;
    T[(seg * 4 + 2) * 65 + row] = f2;
    T[(seg * 4 + 3) * 65 + row] = f3;
  }
  __syncthreads();
#pragma unroll
  for (int p = 0; p < 4; ++p) {
    int s = p * 256 + t;
    int nl = s >> 4, cs = s & 15;
    float f0 = T[nl * 65 + cs * 4 + 0];
    float f1 = T[nl * 65 + cs * 4 + 1];
    float f2 = T[nl * 65 + cs * 4 + 2];
    float f3 = T[nl * 65 + cs * 4 + 3];
    ushort4 u;
    u.x = f2bf(f0); u.y = f2bf(f1); u.z = f2bf(f2); u.w = f2bf(f3);
    *(ushort4*)(xnT + ((size_t)bb * 4096 + n0 + nl) * 512 + c0 + cs * 4) = u;
  }
}

// ---------------- GEMM ----------------
// MODE 0 (QKV): qkv gets V rows only, with j bit-permuted within 64-blocks
//               (u5,u4,u3:2,u1:0 -> u5,u3:2,u4,u1:0) so attn PV reads are b128;
//               qkvT gets Q/K rows only. MODE 1 (proj): +bias+resid f32.
template <int MODE>
__global__ __launch_bounds__(256) void k_gemm(
    const unsigned short* __restrict__ A,
    const unsigned short* __restrict__ Bt,
    const float* __restrict__ bias,
    unsigned short* __restrict__ outA,
    unsigned short* __restrict__ outT,
    const unsigned short* __restrict__ resid,
    float* __restrict__ outF,
    int Mo) {
  __shared__ char lds[34816];
  const int t = threadIdx.x;
  const int lane = t & 63;
  const int g = lane >> 4, ln = lane & 15;
  const int wid = t >> 6, wr = wid >> 1, wc = wid & 1;
  const int bn0 = blockIdx.x * 128, bm0 = blockIdx.y * 128, bb = blockIdx.z;

  const unsigned short* Ab = A + (size_t)bm0 * 512;
  const unsigned short* Bb = Bt + ((size_t)bb * 4096 + bn0) * 512;

  f32x4 acc[4][4];
#pragma unroll
  for (int m = 0; m < 4; ++m)
#pragma unroll
    for (int n = 0; n < 4; ++n) acc[m][n] = f32x4{0.f, 0.f, 0.f, 0.f};

#pragma unroll 1
  for (int kt = 0; kt < 8; ++kt) {
#pragma unroll
    for (int p = 0; p < 4; ++p) {
      int s = p * 256 + t;
      int row = s >> 3;
      int csg = (s & 7) ^ (row & 7);
      g2l16(Ab + (size_t)row * 512 + kt * 64 + csg * 8,
            &lds[(p * 256 + (t & ~63)) * 16]);
    }
#pragma unroll
    for (int p = 0; p < 4; ++p) {
      int s = p * 256 + t;
      int row = s >> 3;
      int csg = (s & 7) ^ (row & 7);
      g2l16(Bb + (size_t)row * 512 + kt * 64 + csg * 8,
            &lds[16384 + (p * 256 + (t & ~63)) * 16]);
    }
    __syncthreads();
#pragma unroll
    for (int kk = 0; kk < 2; ++kk) {
      short8 af[4], bfr[4];
#pragma unroll
      for (int m = 0; m < 4; ++m) {
        int row = wr * 64 + m * 16 + ln;
        int cs = (kk * 4 + g) ^ (row & 7);
        af[m] = *(const short8*)&lds[row * 128 + cs * 16];
      }
#pragma unroll
      for (int n = 0; n < 4; ++n) {
        int row = wc * 64 + n * 16 + ln;
        int cs = (kk * 4 + g) ^ (row & 7);
        bfr[n] = *(const short8*)&lds[16384 + row * 128 + cs * 16];
      }
      __builtin_amdgcn_s_setprio(1);
#pragma unroll
      for (int m = 0; m < 4; ++m)
#pragma unroll
        for (int n = 0; n < 4; ++n)
          acc[m][n] = __builtin_amdgcn_mfma_f32_16x16x32_bf16(af[m], bfr[n], acc[m][n], 0, 0, 0);
      __builtin_amdgcn_s_setprio(0);
    }
    __syncthreads();
  }

  if (MODE == 0) {
#pragma unroll
    for (int m = 0; m < 4; ++m)
#pragma unroll
      for (int n = 0; n < 4; ++n)
#pragma unroll
        for (int r = 0; r < 4; ++r) {
          int ol = wr * 64 + m * 16 + g * 4 + r;
          int jl = wc * 64 + n * 16 + ln;
          int o = bm0 + ol, j = bn0 + jl;
          float v = acc[m][n][r] + bias[o];
          unsigned short bv = f2bf(v);
          if ((o % 192) >= 128) {  // V rows only, j bit-permuted within 64-blocks
            int jp = (j & ~63) | (j & 32) | ((j & 0xC) << 1) | ((j & 16) >> 2) | (j & 3);
            outA[((size_t)bb * 1536 + o) * 4096 + jp] = bv;
          }
          *(unsigned short*)&lds[jl * 272 + ol * 2] = bv;
        }
    __syncthreads();
#pragma unroll
    for (int p = 0; p < 8; ++p) {
      int s = p * 256 + t;
      int jl = s >> 4, cs = s & 15;
      int oo = bm0 + cs * 8;
      if ((oo % 192) < 128) {  // Q,K rows only
        short8 v = *(const short8*)&lds[jl * 272 + cs * 16];
        *(short8*)&outT[((size_t)bb * 4096 + bn0 + jl) * 1536 + oo] = v;
      }
    }
  } else {
#pragma unroll
    for (int m = 0; m < 4; ++m)
#pragma unroll
      for (int n = 0; n < 4; ++n)
#pragma unroll
        for (int r = 0; r < 4; ++r) {
          int o = bm0 + wr * 64 + m * 16 + g * 4 + r;
          int j = bn0 + wc * 64 + n * 16 + ln;
          size_t idx = ((size_t)bb * 512 + o) * 4096 + j;
          outF[idx] = acc[m][n][r] + bias[o] + bf2f(resid[idx]);
        }
  }
}

// ---------------- Flash attention v13: 4 phase domains per CU ----------------
// grid (64 q-tiles of 64, 8 heads, 2 batch) = 1024 blocks, 512 threads (8 waves),
// wave (qw=wid>>1, jw=wid&1) owns 16 q-rows x 32-j slice.
// WHY: every prior variant had exactly 2 barrier-locked phase domains per CU
// (2 blocks/CU), and wall time == serial sum of matrix+trans+VALU pipes in all
// of them -- barrier-synced waves all want the same pipe at the same time.
// Here: 32KB LDS (double buffer) + VGPR<=64 (launch_bounds(512,8)) -> 4
// independent blocks/CU = 4 decorrelated phase domains + 32 waves/CU (chip max).
// Mixed-phase waves on each SIMD let MFMA/trans/LDS pipes overlap across blocks.
// Cost: K/V staged by 2x more blocks (FETCH ~+30MB, far below BW limits).
__global__ __launch_bounds__(512, 8) void k_attn(const unsigned short* __restrict__ qkv,
                                                 const unsigned short* __restrict__ qkvT,
                                                 unsigned short* __restrict__ aT) {
  __shared__ char lds[32768];  // buf*16384: K at +0 (8KB), V at +8192 (8KB)
  const int t = threadIdx.x, lane = t & 63;
  const int g = lane >> 4, ln = lane & 15;
  const int wid = t >> 6;   // 0..7
  const int qw = wid >> 1;  // q-subtile 0..3 (16 rows each)
  const int jw = wid & 1;   // j-slice 0..1
  const int h = blockIdx.y, bb = blockIdx.z;
  const int q0 = blockIdx.x * 64 + qw * 16;

  // K fragment addrs [kk_d][jf]; V fragment addrs [df] (slice jw)
  int kaddr[2][2], vaddr[4];
#pragma unroll
  for (int kk = 0; kk < 2; ++kk)
#pragma unroll
    for (int jf = 0; jf < 2; ++jf) {
      int row = jw * 32 + jf * 16 + ln;
      kaddr[kk][jf] = row * 128 + (((kk * 4 + g) ^ (row & 7)) << 4);
    }
#pragma unroll
  for (int df = 0; df < 4; ++df) {
    int row = df * 16 + ln;
    vaddr[df] = 8192 + row * 128 + (((jw * 4 + g) ^ (row & 7)) << 4);
  }

  // staging: 512 threads x (1 K + 1 V) 16B segment per tile (8KB each)
  const unsigned short* kS;
  const unsigned short* vS;
  int ldst;
  {
    int row = t >> 3, csg = (t & 7) ^ (row & 7);
    kS = qkvT + ((size_t)bb * 4096 + row) * 1536 + 192 * h + 64 + csg * 8;
    vS = qkv + ((size_t)bb * 1536 + 192 * h + 128 + row) * 4096 + csg * 8;
    ldst = (t & ~63) * 16;  // wave-uniform base; g2l16 adds lane*16
  }

  // Q fragments [kk_d], pre-scaled by 0.125*log2(e)
  short8 qf[2];
#pragma unroll
  for (int kk = 0; kk < 2; ++kk) {
    short8 v = *(const short8*)(qkvT + ((size_t)bb * 4096 + q0 + ln) * 1536 +
                                192 * h + kk * 32 + g * 8);
#pragma unroll
    for (int e = 0; e < 8; ++e) {
      float f = bf2f((unsigned short)v[e]) * QSCALE;
      v[e] = (short)f2bf(f);
    }
    qf[kk] = v;
  }

  // all-ones bf16 B fragment for the row-sum MFMA
  const short8 onesb = mk8(0x3F803F80u, 0x3F803F80u, 0x3F803F80u, 0x3F803F80u);

  f32x4 acc[4];
  f32x4 lacc = f32x4{0.f, 0.f, 0.f, 0.f};
#pragma unroll
  for (int df = 0; df < 4; ++df) acc[df] = f32x4{0.f, 0.f, 0.f, 0.f};

  // prologue: stage tile 0 into buf0
  g2l16(kS, &lds[ldst]);
  g2l16(vS, &lds[8192 + ldst]);
  kS += 64 * 1536;
  vS += 64;

  // ---- main loop: QK(slice) -> exp -> pack -> PV(slice) ----
#pragma unroll 2
  for (int jt = 0; jt < 64; ++jt) {
    const int cur = jt & 1;
    const char* B = &lds[cur * 16384];  // vaddr carries the 8192 V base
    asm volatile("s_waitcnt vmcnt(0) lgkmcnt(0)" ::: "memory");
    __builtin_amdgcn_s_barrier();
    __builtin_amdgcn_sched_barrier(0);

    // stage tile jt+1 into the other buffer (safe: lgkmcnt(0) before this
    // barrier means no wave still reads it from iter jt-1)
    if (jt < 63) {
      g2l16(kS, &lds[(cur ^ 1) * 16384 + ldst]);
      g2l16(vS, &lds[(cur ^ 1) * 16384 + 8192 + ldst]);
      kS += 64 * 1536;
      vS += 64;
    }

    // K slice fragments (4 b128, conflict-free)
    short8 kf[2][2];
#pragma unroll
    for (int kk = 0; kk < 2; ++kk)
#pragma unroll
      for (int jf = 0; jf < 2; ++jf) kf[kk][jf] = *(const short8*)(B + kaddr[kk][jf]);

    // QK^T over the slice: w[jf], 4 MFMA, C folded to const zero
    const f32x4 zf = f32x4{0.f, 0.f, 0.f, 0.f};
    f32x4 w[2];
    __builtin_amdgcn_s_setprio(1);
#pragma unroll
    for (int jf = 0; jf < 2; ++jf)
      w[jf] = __builtin_amdgcn_mfma_f32_16x16x32_bf16(kf[0][jf], qf[0], zf, 0, 0, 0);
#pragma unroll
    for (int jf = 0; jf < 2; ++jf)
      w[jf] = __builtin_amdgcn_mfma_f32_16x16x32_bf16(kf[1][jf], qf[1], w[jf], 0, 0, 0);
    __builtin_amdgcn_s_setprio(0);

    // V slice fragments (4 b128) -- issued before exp so ds latency hides there
    short8 vf[4];
#pragma unroll
    for (int df = 0; df < 4; ++df) vf[df] = *(const short8*)(B + vaddr[df]);

    // p = exp2(w), 8 trans ops
#pragma unroll
    for (int jf = 0; jf < 2; ++jf)
#pragma unroll
      for (int r = 0; r < 4; ++r) w[jf][r] = __builtin_amdgcn_exp2f(w[jf][r]);

    // pack to bf16 A-fragment (K=32 contraction block = this wave's j-slice)
    short8 pf = mk8(cvtpk(w[0][0], w[0][1]), cvtpk(w[0][2], w[0][3]),
                    cvtpk(w[1][0], w[1][1]), cvtpk(w[1][2], w[1][3]));

    // PV over the slice + ones row-sum, 5 MFMA
    __builtin_amdgcn_s_setprio(1);
#pragma unroll
    for (int df = 0; df < 4; ++df)
      acc[df] = __builtin_amdgcn_mfma_f32_16x16x32_bf16(pf, vf[df], acc[df], 0, 0, 0);
    lacc = __builtin_amdgcn_mfma_f32_16x16x32_bf16(pf, onesb, lacc, 0, 0, 0);
    __builtin_amdgcn_s_setprio(0);
  }

  // ---- epilogue: combine jw partials via LDS (reuse K/V buffers), then write ----
  __syncthreads();
  float* cb = (float*)lds;
  const int cbase = qw * 1280;  // floats; 5 KB per qw, 20 KB total
  if (jw == 1) {
#pragma unroll
    for (int df = 0; df < 4; ++df)
      *(f32x4*)&cb[cbase + (df * 64 + lane) * 4] = acc[df];
    *(f32x4*)&cb[cbase + 1024 + lane * 4] = lacc;
  }
  __syncthreads();
  if (jw == 0) {
#pragma unroll
    for (int df = 0; df < 4; ++df)
      acc[df] += *(const f32x4*)&cb[cbase + (df * 64 + lane) * 4];
    lacc += *(const f32x4*)&cb[cbase + 1024 + lane * 4];
#pragma unroll
    for (int r = 0; r < 4; ++r) {
      float inv = 1.f / lacc[r];
      int row = q0 + g * 4 + r;
#pragma unroll
      for (int df = 0; df < 4; ++df)
        aT[((size_t)bb * 4096 + row) * 512 + h * 64 + df * 16 + ln] =
            f2bf(acc[df][r] * inv);
    }
  }
}

// ---------------- launcher ----------------
extern "C" void kernel_launch(void* const* d_in, const int* in_sizes, int n_in,
                              void* d_out, int out_size, void* d_ws, size_t ws_size,
                              hipStream_t stream) {
  const float* x     = (const float*)d_in[0];
  const float* gnw   = (const float*)d_in[1];
  const float* gnb   = (const float*)d_in[2];
  const float* qkvw  = (const float*)d_in[3];
  const float* qkvb  = (const float*)d_in[4];
  const float* projw = (const float*)d_in[5];
  const float* projb = (const float*)d_in[6];
  float* out = (float*)d_out;
  char* ws = (char*)d_ws;

  const size_t OFF_WQ   = 0;
  const size_t OFF_WP   = 1572864;
  const size_t OFF_XN   = 2097152;
  const size_t OFF_XNT  = 10485760;
  const size_t OFF_QKV  = 18874368;
  const size_t OFF_QKVT = 44040192;
  const size_t OFF_AT   = 69206016;
  const size_t OFF_PART = 77594624;

  unsigned short* wq   = (unsigned short*)(ws + OFF_WQ);
  unsigned short* wp   = (unsigned short*)(ws + OFF_WP);
  unsigned short* xn   = (unsigned short*)(ws + OFF_XN);
  unsigned short* xnT  = (unsigned short*)(ws + OFF_XNT);
  unsigned short* qkv  = (unsigned short*)(ws + OFF_QKV);
  unsigned short* qkvT = (unsigned short*)(ws + OFF_QKVT);
  unsigned short* aT   = (unsigned short*)(ws + OFF_AT);
  float* part  = (float*)(ws + OFF_PART);

  k_wgn<<<dim3(2048), dim3(256), 0, stream>>>(qkvw, projw, wq, wp, x, part);
  k_gnnorm<<<dim3(64, 8, 2), dim3(256), 0, stream>>>(x, gnw, gnb, part, xn, xnT);
  k_gemm<0><<<dim3(32, 12, 2), dim3(256), 0, stream>>>(wq, xnT, qkvb, qkv, qkvT, nullptr, nullptr, 1536);
  k_attn<<<dim3(64, 8, 2), dim3(512), 0, stream>>>(qkv, qkvT, aT);
  k_gemm<1><<<dim3(32, 4, 2), dim3(256), 0, stream>>>(wp, aT, projb, nullptr, nullptr, xn, out, 512);
}

// Round 10
// 131.131 us; speedup vs baseline: 2.4867x; 2.4867x over previous
//
#include <hip/hip_runtime.h>
#include <cstdint>
#include <cstddef>

typedef __attribute__((ext_vector_type(8))) short short8;
typedef __attribute__((ext_vector_type(4))) float f32x4;
typedef __attribute__((ext_vector_type(16))) float f32x16;

#define QSCALE 0.18033688011112043f  // 0.125 * log2(e)

__device__ __forceinline__ float bf2f(unsigned short u) {
  return __uint_as_float(((unsigned)u) << 16);
}
__device__ __forceinline__ unsigned short f2bf(float f) {
  unsigned u = __float_as_uint(f);
  u += 0x7fffu + ((u >> 16) & 1u);
  return (unsigned short)(u >> 16);
}
// pack two f32 -> 2 bf16 (RNE) in one VALU op: lo=a, hi=b
__device__ __forceinline__ unsigned cvtpk(float a, float b) {
  unsigned r;
  asm("v_cvt_pk_bf16_f32 %0, %1, %2" : "=v"(r) : "v"(a), "v"(b));
  return r;
}
__device__ __forceinline__ short8 mk8(unsigned a, unsigned b, unsigned c, unsigned d) {
  union { unsigned u[4]; short8 s; } x;
  x.u[0] = a; x.u[1] = b; x.u[2] = c; x.u[3] = d;
  return x.s;
}
__device__ __forceinline__ void g2l16(const void* g, void* l) {
  __builtin_amdgcn_global_load_lds(
      (const __attribute__((address_space(1))) unsigned int*)g,
      (__attribute__((address_space(3))) unsigned int*)l, 16, 0, 0);
}

// ---------------- fused: weight conversion + GroupNorm partial sums ----------------
__global__ __launch_bounds__(256) void k_wgn(const float* __restrict__ wqf,
                                             const float* __restrict__ wpf,
                                             unsigned short* __restrict__ wq,
                                             unsigned short* __restrict__ wp,
                                             const float* __restrict__ x,
                                             float* __restrict__ part) {
  __shared__ float red[8];
  const int blk = blockIdx.x;
  const int t = threadIdx.x;
  if (blk < 1024) {
    int i = blk * 256 + t;
    if (i < 196608) {
      float4 v = ((const float4*)wqf)[i];
      ushort4 u;
      u.x = f2bf(v.x); u.y = f2bf(v.y); u.z = f2bf(v.z); u.w = f2bf(v.w);
      ((ushort4*)wq)[i] = u;
    } else {
      int k = i - 196608;
      float4 v = ((const float4*)wpf)[k];
      ushort4 u;
      u.x = f2bf(v.x); u.y = f2bf(v.y); u.z = f2bf(v.z); u.w = f2bf(v.w);
      ((ushort4*)wp)[k] = u;
    }
  } else {
    int b2 = blk - 1024;
    int bg = b2 >> 4, slice = b2 & 15;
    const float4* base = (const float4*)(x + (size_t)bg * 65536 + (size_t)slice * 4096);
    float s = 0.f, q = 0.f;
#pragma unroll
    for (int i = 0; i < 4; ++i) {
      float4 v = base[t + i * 256];
      s += v.x + v.y + v.z + v.w;
      q += v.x * v.x + v.y * v.y + v.z * v.z + v.w * v.w;
    }
#pragma unroll
    for (int off = 1; off < 64; off <<= 1) {
      s += __shfl_xor(s, off);
      q += __shfl_xor(q, off);
    }
    int wid = t >> 6;
    if ((t & 63) == 0) { red[wid * 2] = s; red[wid * 2 + 1] = q; }
    __syncthreads();
    if (t == 0) {
      float S = red[0] + red[2] + red[4] + red[6];
      float Q = red[1] + red[3] + red[5] + red[7];
      part[b2 * 2] = S;
      part[b2 * 2 + 1] = Q;
    }
  }
}

// ---------------- GroupNorm normalize: xn + xnT (stats fused in) ----------------
__global__ __launch_bounds__(256) void k_gnnorm(const float* __restrict__ x,
                                                const float* __restrict__ gnw,
                                                const float* __restrict__ gnb,
                                                const float* __restrict__ part,
                                                unsigned short* __restrict__ xn,
                                                unsigned short* __restrict__ xnT) {
  __shared__ float T[64 * 65];
  __shared__ float sstats[8];  // 4 groups x (mean, rstd)
  const int t = threadIdx.x;
  const int n0 = blockIdx.x * 64, c0 = blockIdx.y * 64, bb = blockIdx.z;
  if (t < 4) {
    int gg = bb * 32 + (c0 >> 4) + t;
    float S = 0.f, Q = 0.f;
#pragma unroll
    for (int i = 0; i < 16; ++i) {
      S += part[(gg * 16 + i) * 2];
      Q += part[(gg * 16 + i) * 2 + 1];
    }
    float mean = S * (1.f / 65536.f);
    float var = Q * (1.f / 65536.f) - mean * mean;
    sstats[t * 2] = mean;
    sstats[t * 2 + 1] = rsqrtf(var + 1e-6f);
  }
  __syncthreads();
#pragma unroll
  for (int p = 0; p < 4; ++p) {
    int s = p * 256 + t;
    int row = s >> 4, seg = s & 15;
    int c = c0 + row;
    float mean = sstats[(row >> 4) * 2], rstd = sstats[(row >> 4) * 2 + 1];
    float gw = gnw[c] * rstd;
    float gb = gnb[c] - mean * gw;
    float4 v = *(const float4*)(x + ((size_t)bb * 512 + c) * 4096 + n0 + seg * 4);
    float f0 = v.x * gw + gb, f1 = v.y * gw + gb, f2 = v.z * gw + gb, f3 = v.w * gw + gb;
    ushort4 u;
    u.x = f2bf(f0); u.y = f2bf(f1); u.z = f2bf(f2); u.w = f2bf(f3);
    *(ushort4*)(xn + ((size_t)bb * 512 + c) * 4096 + n0 + seg * 4) = u;
    T[(seg * 4 + 0) * 65 + row] = f0;
    T[(seg * 4 + 1) * 65 + row] = f1;
    T[(seg * 4 + 2) * 65 + row] = f2;
    T[(seg * 4 + 3) * 65 + row] = f3;
  }
  __syncthreads();
#pragma unroll
  for (int p = 0; p < 4; ++p) {
    int s = p * 256 + t;
    int nl = s >> 4, cs = s & 15;
    float f0 = T[nl * 65 + cs * 4 + 0];
    float f1 = T[nl * 65 + cs * 4 + 1];
    float f2 = T[nl * 65 + cs * 4 + 2];
    float f3 = T[nl * 65 + cs * 4 + 3];
    ushort4 u;
    u.x = f2bf(f0); u.y = f2bf(f1); u.z = f2bf(f2); u.w = f2bf(f3);
    *(ushort4*)(xnT + ((size_t)bb * 4096 + n0 + nl) * 512 + c0 + cs * 4) = u;
  }
}

// ---------------- GEMM ----------------
// MODE 0 (QKV): qkv gets V rows only, j bits 2<->3 swapped within 64-blocks
//               (matches attn v14's 32x32 PV fragment placement);
//               qkvT gets Q/K rows (straight layout). MODE 1: +bias+resid f32.
template <int MODE>
__global__ __launch_bounds__(256) void k_gemm(
    const unsigned short* __restrict__ A,
    const unsigned short* __restrict__ Bt,
    const float* __restrict__ bias,
    unsigned short* __restrict__ outA,
    unsigned short* __restrict__ outT,
    const unsigned short* __restrict__ resid,
    float* __restrict__ outF,
    int Mo) {
  __shared__ char lds[34816];
  const int t = threadIdx.x;
  const int lane = t & 63;
  const int g = lane >> 4, ln = lane & 15;
  const int wid = t >> 6, wr = wid >> 1, wc = wid & 1;
  const int bn0 = blockIdx.x * 128, bm0 = blockIdx.y * 128, bb = blockIdx.z;

  const unsigned short* Ab = A + (size_t)bm0 * 512;
  const unsigned short* Bb = Bt + ((size_t)bb * 4096 + bn0) * 512;

  f32x4 acc[4][4];
#pragma unroll
  for (int m = 0; m < 4; ++m)
#pragma unroll
    for (int n = 0; n < 4; ++n) acc[m][n] = f32x4{0.f, 0.f, 0.f, 0.f};

#pragma unroll 1
  for (int kt = 0; kt < 8; ++kt) {
#pragma unroll
    for (int p = 0; p < 4; ++p) {
      int s = p * 256 + t;
      int row = s >> 3;
      int csg = (s & 7) ^ (row & 7);
      g2l16(Ab + (size_t)row * 512 + kt * 64 + csg * 8,
            &lds[(p * 256 + (t & ~63)) * 16]);
    }
#pragma unroll
    for (int p = 0; p < 4; ++p) {
      int s = p * 256 + t;
      int row = s >> 3;
      int csg = (s & 7) ^ (row & 7);
      g2l16(Bb + (size_t)row * 512 + kt * 64 + csg * 8,
            &lds[16384 + (p * 256 + (t & ~63)) * 16]);
    }
    __syncthreads();
#pragma unroll
    for (int kk = 0; kk < 2; ++kk) {
      short8 af[4], bfr[4];
#pragma unroll
      for (int m = 0; m < 4; ++m) {
        int row = wr * 64 + m * 16 + ln;
        int cs = (kk * 4 + g) ^ (row & 7);
        af[m] = *(const short8*)&lds[row * 128 + cs * 16];
      }
#pragma unroll
      for (int n = 0; n < 4; ++n) {
        int row = wc * 64 + n * 16 + ln;
        int cs = (kk * 4 + g) ^ (row & 7);
        bfr[n] = *(const short8*)&lds[16384 + row * 128 + cs * 16];
      }
      __builtin_amdgcn_s_setprio(1);
#pragma unroll
      for (int m = 0; m < 4; ++m)
#pragma unroll
        for (int n = 0; n < 4; ++n)
          acc[m][n] = __builtin_amdgcn_mfma_f32_16x16x32_bf16(af[m], bfr[n], acc[m][n], 0, 0, 0);
      __builtin_amdgcn_s_setprio(0);
    }
    __syncthreads();
  }

  if (MODE == 0) {
#pragma unroll
    for (int m = 0; m < 4; ++m)
#pragma unroll
      for (int n = 0; n < 4; ++n)
#pragma unroll
        for (int r = 0; r < 4; ++r) {
          int ol = wr * 64 + m * 16 + g * 4 + r;
          int jl = wc * 64 + n * 16 + ln;
          int o = bm0 + ol, j = bn0 + jl;
          float v = acc[m][n][r] + bias[o];
          unsigned short bv = f2bf(v);
          if ((o % 192) >= 128) {  // V rows: swap j bits 2<->3 within 64-blocks
            int jp = (j & ~0xC) | ((j & 4) << 1) | ((j & 8) >> 1);
            outA[((size_t)bb * 1536 + o) * 4096 + jp] = bv;
          }
          *(unsigned short*)&lds[jl * 272 + ol * 2] = bv;
        }
    __syncthreads();
#pragma unroll
    for (int p = 0; p < 8; ++p) {
      int s = p * 256 + t;
      int jl = s >> 4, cs = s & 15;
      int oo = bm0 + cs * 8;
      if ((oo % 192) < 128) {  // Q,K rows only (straight layout)
        short8 v = *(const short8*)&lds[jl * 272 + cs * 16];
        *(short8*)&outT[((size_t)bb * 4096 + bn0 + jl) * 1536 + oo] = v;
      }
    }
  } else {
#pragma unroll
    for (int m = 0; m < 4; ++m)
#pragma unroll
      for (int n = 0; n < 4; ++n)
#pragma unroll
        for (int r = 0; r < 4; ++r) {
          int o = bm0 + wr * 64 + m * 16 + g * 4 + r;
          int j = bn0 + wc * 64 + n * 16 + ln;
          size_t idx = ((size_t)bb * 512 + o) * 4096 + j;
          outF[idx] = acc[m][n][r] + bias[o] + bf2f(resid[idx]);
        }
  }
}

// ---------------- Flash attention v14: 32x32x16 MFMA (26% fewer matrix cycles) ----------------
// grid (32 q-tiles of 128, 8 heads, 2 batch) = 512 blocks, 512 threads (8 waves).
// Wave (qw=wid>>1, jw=wid&1): 32 q-rows x 32-j slice. v9 skeleton (triple-buffered
// 48KB LDS, same staging, 1 barrier/iter) but all MFMAs are 32x32x16:
//   QK: 4 MFMA (d=64 = 4 k-chunks); PV: 4 MFMA (2 j-chunks x 2 d-blocks).
//   vs v9's 18x 16x16x32: same FLOPs, -26% matrix cycles (2382 vs 2075 TF rate),
//   and the MFMA-ones row-sum is replaced by a 15-add VALU tree (lane holds the
//   full P row for q=lane&31 in the 32x32 C layout; epilogue shfl_xor(32) merges
//   the partner half).
// Fragment placements (HW k-mapping is free; only A/B consistency matters):
//   QK uses contiguous k -> Q/K fragments are straight 16B reads (storage unchanged).
//   PV uses the C/D-native split -> pf packs from OWN regs (8 cvt_pk, no permlane)
//   and V is stored with j bits 2<->3 swapped (k_gemm<0>).
__global__ __launch_bounds__(512, 4) void k_attn(const unsigned short* __restrict__ qkv,
                                                 const unsigned short* __restrict__ qkvT,
                                                 unsigned short* __restrict__ aT) {
  __shared__ char lds[49152];  // K: cur*8192, V: 24576 + cur*8192
  const int t = threadIdx.x, lane = t & 63;
  const int hi = lane >> 5, l31 = lane & 31;
  const int wid = t >> 6;   // 0..7
  const int qw = wid >> 1;  // q-subtile 0..3 (32 rows each)
  const int jw = wid & 1;   // j-slice 0..1
  const int h = blockIdx.y, bb = blockIdx.z;
  const int q0 = blockIdx.x * 128 + qw * 32;

  // K fragment addrs [c]: A[m=j=jw*32+l31][k contiguous]: 16B at group (2c+hi)
  int kaddr[4];
  {
    int row = jw * 32 + l31;
#pragma unroll
    for (int c = 0; c < 4; ++c)
      kaddr[c] = row * 128 + (((2 * c + hi) ^ (row & 7)) << 4);
  }
  // V fragment addrs [c2][db]: B[k=j (swapped storage)][n=d=db*32+l31]
  int vaddr[2][2];
#pragma unroll
  for (int c2 = 0; c2 < 2; ++c2)
#pragma unroll
    for (int db = 0; db < 2; ++db) {
      int row = db * 32 + l31;
      vaddr[c2][db] = 24576 + row * 128 + (((jw * 4 + 2 * c2 + hi) ^ (row & 7)) << 4);
    }

  // staging: 512 threads x (1 K + 1 V) 16B segment per tile (8KB each)
  const unsigned short* kS;
  const unsigned short* vS;
  int ldst;
  {
    int row = t >> 3, csg = (t & 7) ^ (row & 7);
    kS = qkvT + ((size_t)bb * 4096 + row) * 1536 + 192 * h + 64 + csg * 8;
    vS = qkv + ((size_t)bb * 1536 + 192 * h + 128 + row) * 4096 + csg * 8;
    ldst = (t & ~63) * 16;  // wave-uniform base; g2l16 adds lane*16
  }

  // Q fragments [c]: B[k contiguous][n=q=l31]: 16B at group (2c+hi), QSCALE'd
  short8 qf[4];
#pragma unroll
  for (int c = 0; c < 4; ++c) {
    short8 v = *(const short8*)(qkvT + ((size_t)bb * 4096 + q0 + l31) * 1536 +
                                192 * h + (2 * c + hi) * 8);
#pragma unroll
    for (int e = 0; e < 8; ++e) {
      float f = bf2f((unsigned short)v[e]) * QSCALE;
      v[e] = (short)f2bf(f);
    }
    qf[c] = v;
  }

  f32x16 acc0 = {0.f,0.f,0.f,0.f,0.f,0.f,0.f,0.f,0.f,0.f,0.f,0.f,0.f,0.f,0.f,0.f};
  f32x16 acc1 = {0.f,0.f,0.f,0.f,0.f,0.f,0.f,0.f,0.f,0.f,0.f,0.f,0.f,0.f,0.f,0.f};
  float lsum = 0.f;

  // prologue: stage tiles 0 (buf0) and 1 (buf1)
#pragma unroll
  for (int jt = 0; jt < 2; ++jt) {
    g2l16(kS, &lds[jt * 8192 + ldst]);
    g2l16(vS, &lds[24576 + jt * 8192 + ldst]);
    kS += 64 * 1536;
    vS += 64;
  }

  // ---- main loop ----
#pragma unroll 3
  for (int jt = 0; jt < 64; ++jt) {
    const int cur = jt % 3;
    const char* Kc = &lds[cur * 8192];  // vaddr carries the 24576 V base
    if (jt < 63) {
      asm volatile("s_waitcnt vmcnt(2) lgkmcnt(0)" ::: "memory");
    } else {
      asm volatile("s_waitcnt vmcnt(0) lgkmcnt(0)" ::: "memory");
    }
    __builtin_amdgcn_s_barrier();
    __builtin_amdgcn_sched_barrier(0);

    // stage tile jt+2 into buf (jt+2)%3
    if (jt < 62) {
      int nb = (jt + 2) % 3;
      g2l16(kS, &lds[nb * 8192 + ldst]);
      g2l16(vS, &lds[24576 + nb * 8192 + ldst]);
      kS += 64 * 1536;
      vS += 64;
    }

    // K fragments (4 b128)
    short8 kf[4];
#pragma unroll
    for (int c = 0; c < 4; ++c) kf[c] = *(const short8*)(Kc + kaddr[c]);

    // QK^T: w = P^T (col=q=l31, row=j=(r&3)+8*(r>>2)+4*hi), 4 MFMA
    const f32x16 zf = {0.f,0.f,0.f,0.f,0.f,0.f,0.f,0.f,0.f,0.f,0.f,0.f,0.f,0.f,0.f,0.f};
    f32x16 w;
    __builtin_amdgcn_s_setprio(1);
    w = __builtin_amdgcn_mfma_f32_32x32x16_bf16(kf[0], qf[0], zf, 0, 0, 0);
    w = __builtin_amdgcn_mfma_f32_32x32x16_bf16(kf[1], qf[1], w, 0, 0, 0);
    w = __builtin_amdgcn_mfma_f32_32x32x16_bf16(kf[2], qf[2], w, 0, 0, 0);
    w = __builtin_amdgcn_mfma_f32_32x32x16_bf16(kf[3], qf[3], w, 0, 0, 0);
    __builtin_amdgcn_s_setprio(0);

    // V fragments (4 b128) -- issued before exp so ds latency hides there
    short8 vf[2][2];
#pragma unroll
    for (int c2 = 0; c2 < 2; ++c2)
#pragma unroll
      for (int db = 0; db < 2; ++db) vf[c2][db] = *(const short8*)(Kc + vaddr[c2][db]);

    // p = exp2(w), 16 trans ops
#pragma unroll
    for (int r = 0; r < 16; ++r) w[r] = __builtin_amdgcn_exp2f(w[r]);

    // row-sum for q=l31 (this lane's 16 j's; partner half merged in epilogue)
    {
      float s0 = w[0] + w[1], s1 = w[2] + w[3], s2 = w[4] + w[5], s3 = w[6] + w[7];
      float s4 = w[8] + w[9], s5 = w[10] + w[11], s6 = w[12] + w[13], s7 = w[14] + w[15];
      s0 += s1; s2 += s3; s4 += s5; s6 += s7;
      s0 += s2; s4 += s6;
      lsum += s0 + s4;
    }

    // pack to PV A-fragments from OWN regs (placement matches V's swapped storage)
    short8 pf[2];
#pragma unroll
    for (int c2 = 0; c2 < 2; ++c2)
      pf[c2] = mk8(cvtpk(w[8 * c2 + 0], w[8 * c2 + 1]),
                   cvtpk(w[8 * c2 + 2], w[8 * c2 + 3]),
                   cvtpk(w[8 * c2 + 4], w[8 * c2 + 5]),
                   cvtpk(w[8 * c2 + 6], w[8 * c2 + 7]));

    // PV: 4 MFMA
    __builtin_amdgcn_s_setprio(1);
    acc0 = __builtin_amdgcn_mfma_f32_32x32x16_bf16(pf[0], vf[0][0], acc0, 0, 0, 0);
    acc1 = __builtin_amdgcn_mfma_f32_32x32x16_bf16(pf[0], vf[0][1], acc1, 0, 0, 0);
    acc0 = __builtin_amdgcn_mfma_f32_32x32x16_bf16(pf[1], vf[1][0], acc0, 0, 0, 0);
    acc1 = __builtin_amdgcn_mfma_f32_32x32x16_bf16(pf[1], vf[1][1], acc1, 0, 0, 0);
    __builtin_amdgcn_s_setprio(0);
  }

  // ---- epilogue ----
  lsum += __shfl_xor(lsum, 32);  // full 32-j slice sum for q=l31

  __syncthreads();
  float* cb = (float*)lds;             // acc combine: 8192 floats (32 KB)
  float* lb = (float*)(lds + 32768);   // lsum: 128 floats
  if (jw == 1) {
#pragma unroll
    for (int db = 0; db < 2; ++db) {
#pragma unroll
      for (int rr = 0; rr < 4; ++rr) {
        f32x4 v;
#pragma unroll
        for (int e = 0; e < 4; ++e) v[e] = db ? acc1[rr * 4 + e] : acc0[rr * 4 + e];
        *(f32x4*)&cb[(qw * 2 + db) * 1024 + lane * 16 + rr * 4] = v;
      }
    }
    if (!hi) lb[qw * 32 + l31] = lsum;
  }
  __syncthreads();
  if (jw == 0) {
#pragma unroll
    for (int db = 0; db < 2; ++db) {
#pragma unroll
      for (int rr = 0; rr < 4; ++rr) {
        f32x4 v = *(const f32x4*)&cb[(qw * 2 + db) * 1024 + lane * 16 + rr * 4];
#pragma unroll
        for (int e = 0; e < 4; ++e) {
          if (db) acc1[rr * 4 + e] += v[e];
          else    acc0[rr * 4 + e] += v[e];
        }
      }
    }
    float ltot = lsum + lb[qw * 32 + l31];
    if (!hi) lb[qw * 32 + l31] = ltot;
  }
  __syncthreads();
  if (jw == 0) {
#pragma unroll
    for (int r = 0; r < 16; ++r) {
      int cr = (r & 3) + 8 * (r >> 2) + 4 * hi;
      float inv = 1.f / lb[qw * 32 + cr];
      int row = q0 + cr;
      aT[((size_t)bb * 4096 + row) * 512 + h * 64 + l31] = f2bf(acc0[r] * inv);
      aT[((size_t)bb * 4096 + row) * 512 + h * 64 + 32 + l31] = f2bf(acc1[r] * inv);
    }
  }
}

// ---------------- launcher ----------------
extern "C" void kernel_launch(void* const* d_in, const int* in_sizes, int n_in,
                              void* d_out, int out_size, void* d_ws, size_t ws_size,
                              hipStream_t stream) {
  const float* x     = (const float*)d_in[0];
  const float* gnw   = (const float*)d_in[1];
  const float* gnb   = (const float*)d_in[2];
  const float* qkvw  = (const float*)d_in[3];
  const float* qkvb  = (const float*)d_in[4];
  const float* projw = (const float*)d_in[5];
  const float* projb = (const float*)d_in[6];
  float* out = (float*)d_out;
  char* ws = (char*)d_ws;

  const size_t OFF_WQ   = 0;
  const size_t OFF_WP   = 1572864;
  const size_t OFF_XN   = 2097152;
  const size_t OFF_XNT  = 10485760;
  const size_t OFF_QKV  = 18874368;
  const size_t OFF_QKVT = 44040192;
  const size_t OFF_AT   = 69206016;
  const size_t OFF_PART = 77594624;

  unsigned short* wq   = (unsigned short*)(ws + OFF_WQ);
  unsigned short* wp   = (unsigned short*)(ws + OFF_WP);
  unsigned short* xn   = (unsigned short*)(ws + OFF_XN);
  unsigned short* xnT  = (unsigned short*)(ws + OFF_XNT);
  unsigned short* qkv  = (unsigned short*)(ws + OFF_QKV);
  unsigned short* qkvT = (unsigned short*)(ws + OFF_QKVT);
  unsigned short* aT   = (unsigned short*)(ws + OFF_AT);
  float* part  = (float*)(ws + OFF_PART);

  k_wgn<<<dim3(2048), dim3(256), 0, stream>>>(qkvw, projw, wq, wp, x, part);
  k_gnnorm<<<dim3(64, 8, 2), dim3(256), 0, stream>>>(x, gnw, gnb, part, xn, xnT);
  k_gemm<0><<<dim3(32, 12, 2), dim3(256), 0, stream>>>(wq, xnT, qkvb, qkv, qkvT, nullptr, nullptr, 1536);
  k_attn<<<dim3(32, 8, 2), dim3(512), 0, stream>>>(qkv, qkvT, aT);
  k_gemm<1><<<dim3(32, 4, 2), dim3(256), 0, stream>>>(wp, aT, projb, nullptr, nullptr, xn, out, 512);
}

// Round 11
// 125.113 us; speedup vs baseline: 2.6063x; 1.0481x over previous
//
#include <hip/hip_runtime.h>
#include <cstdint>
#include <cstddef>

typedef __attribute__((ext_vector_type(8))) short short8;
typedef __attribute__((ext_vector_type(4))) float f32x4;

#define QSCALE 0.18033688011112043f  // 0.125 * log2(e)

__device__ __forceinline__ float bf2f(unsigned short u) {
  return __uint_as_float(((unsigned)u) << 16);
}
__device__ __forceinline__ unsigned short f2bf(float f) {
  unsigned u = __float_as_uint(f);
  u += 0x7fffu + ((u >> 16) & 1u);
  return (unsigned short)(u >> 16);
}
// pack two f32 -> 2 bf16 (RNE) in one VALU op: lo=a, hi=b
__device__ __forceinline__ unsigned cvtpk(float a, float b) {
  unsigned r;
  asm("v_cvt_pk_bf16_f32 %0, %1, %2" : "=v"(r) : "v"(a), "v"(b));
  return r;
}
__device__ __forceinline__ short8 mk8(unsigned a, unsigned b, unsigned c, unsigned d) {
  union { unsigned u[4]; short8 s; } x;
  x.u[0] = a; x.u[1] = b; x.u[2] = c; x.u[3] = d;
  return x.s;
}
__device__ __forceinline__ void g2l16(const void* g, void* l) {
  __builtin_amdgcn_global_load_lds(
      (const __attribute__((address_space(1))) unsigned int*)g,
      (__attribute__((address_space(3))) unsigned int*)l, 16, 0, 0);
}

// ---------------- fused: weight conversion + GroupNorm partial sums ----------------
// blocks [0,1024): f32->bf16 weight convert; blocks [1024,2048): GN partial sums.
__global__ __launch_bounds__(256) void k_wgn(const float* __restrict__ wqf,
                                             const float* __restrict__ wpf,
                                             unsigned short* __restrict__ wq,
                                             unsigned short* __restrict__ wp,
                                             const float* __restrict__ x,
                                             float* __restrict__ part) {
  __shared__ float red[8];
  const int blk = blockIdx.x;
  const int t = threadIdx.x;
  if (blk < 1024) {
    int i = blk * 256 + t;
    if (i < 196608) {
      float4 v = ((const float4*)wqf)[i];
      ushort4 u;
      u.x = f2bf(v.x); u.y = f2bf(v.y); u.z = f2bf(v.z); u.w = f2bf(v.w);
      ((ushort4*)wq)[i] = u;
    } else {
      int k = i - 196608;
      float4 v = ((const float4*)wpf)[k];
      ushort4 u;
      u.x = f2bf(v.x); u.y = f2bf(v.y); u.z = f2bf(v.z); u.w = f2bf(v.w);
      ((ushort4*)wp)[k] = u;
    }
  } else {
    int b2 = blk - 1024;
    int bg = b2 >> 4, slice = b2 & 15;
    const float4* base = (const float4*)(x + (size_t)bg * 65536 + (size_t)slice * 4096);
    float s = 0.f, q = 0.f;
#pragma unroll
    for (int i = 0; i < 4; ++i) {
      float4 v = base[t + i * 256];
      s += v.x + v.y + v.z + v.w;
      q += v.x * v.x + v.y * v.y + v.z * v.z + v.w * v.w;
    }
#pragma unroll
    for (int off = 1; off < 64; off <<= 1) {
      s += __shfl_xor(s, off);
      q += __shfl_xor(q, off);
    }
    int wid = t >> 6;
    if ((t & 63) == 0) { red[wid * 2] = s; red[wid * 2 + 1] = q; }
    __syncthreads();
    if (t == 0) {
      float S = red[0] + red[2] + red[4] + red[6];
      float Q = red[1] + red[3] + red[5] + red[7];
      part[b2 * 2] = S;
      part[b2 * 2 + 1] = Q;
    }
  }
}

// ---------------- GroupNorm stage 2 ----------------
__global__ void k_gnfin(const float* __restrict__ part, float* __restrict__ stats) {
  int t = threadIdx.x;
  float S = 0.f, Q = 0.f;
#pragma unroll
  for (int i = 0; i < 16; ++i) {
    S += part[(t * 16 + i) * 2];
    Q += part[(t * 16 + i) * 2 + 1];
  }
  float mean = S * (1.f / 65536.f);
  float var = Q * (1.f / 65536.f) - mean * mean;
  stats[t * 2] = mean;
  stats[t * 2 + 1] = rsqrtf(var + 1e-6f);
}

// ---------------- GroupNorm normalize: xn + xnT ----------------
__global__ __launch_bounds__(256) void k_gnnorm(const float* __restrict__ x,
                                                const float* __restrict__ gnw,
                                                const float* __restrict__ gnb,
                                                const float* __restrict__ stats,
                                                unsigned short* __restrict__ xn,
                                                unsigned short* __restrict__ xnT) {
  __shared__ float T[64 * 65];
  const int t = threadIdx.x;
  const int n0 = blockIdx.x * 64, c0 = blockIdx.y * 64, bb = blockIdx.z;
#pragma unroll
  for (int p = 0; p < 4; ++p) {
    int s = p * 256 + t;
    int row = s >> 4, seg = s & 15;
    int c = c0 + row;
    int gi = bb * 32 + (c >> 4);
    float mean = stats[gi * 2], rstd = stats[gi * 2 + 1];
    float gw = gnw[c] * rstd;
    float gb = gnb[c] - mean * gw;
    float4 v = *(const float4*)(x + ((size_t)bb * 512 + c) * 4096 + n0 + seg * 4);
    float f0 = v.x * gw + gb, f1 = v.y * gw + gb, f2 = v.z * gw + gb, f3 = v.w * gw + gb;
    ushort4 u;
    u.x = f2bf(f0); u.y = f2bf(f1); u.z = f2bf(f2); u.w = f2bf(f3);
    *(ushort4*)(xn + ((size_t)bb * 512 + c) * 4096 + n0 + seg * 4) = u;
    T[(seg * 4 + 0) * 65 + row] = f0;
    T[(seg * 4 + 1) * 65 + row] = f1;
    T[(seg * 4 + 2) * 65 + row] = f2;
    T[(seg * 4 + 3) * 65 + row] = f3;
  }
  __syncthreads();
#pragma unroll
  for (int p = 0; p < 4; ++p) {
    int s = p * 256 + t;
    int nl = s >> 4, cs = s & 15;
    float f0 = T[nl * 65 + cs * 4 + 0];
    float f1 = T[nl * 65 + cs * 4 + 1];
    float f2 = T[nl * 65 + cs * 4 + 2];
    float f3 = T[nl * 65 + cs * 4 + 3];
    ushort4 u;
    u.x = f2bf(f0); u.y = f2bf(f1); u.z = f2bf(f2); u.w = f2bf(f3);
    *(ushort4*)(xnT + ((size_t)bb * 4096 + n0 + nl) * 512 + c0 + cs * 4) = u;
  }
}

// ---------------- GEMM ----------------
// MODE 0 (QKV): qkv gets V rows only, with j bit-permuted within 64-blocks
//               (u5,u4,u3:2,u1:0 -> u5,u3:2,u4,u1:0) so attn PV reads are b128;
//               qkvT gets Q/K rows only. MODE 1 (proj): +bias+resid f32.
template <int MODE>
__global__ __launch_bounds__(256) void k_gemm(
    const unsigned short* __restrict__ A,
    const unsigned short* __restrict__ Bt,
    const float* __restrict__ bias,
    unsigned short* __restrict__ outA,
    unsigned short* __restrict__ outT,
    const unsigned short* __restrict__ resid,
    float* __restrict__ outF,
    int Mo) {
  __shared__ char lds[34816];
  const int t = threadIdx.x;
  const int lane = t & 63;
  const int g = lane >> 4, ln = lane & 15;
  const int wid = t >> 6, wr = wid >> 1, wc = wid & 1;
  const int bn0 = blockIdx.x * 128, bm0 = blockIdx.y * 128, bb = blockIdx.z;

  const unsigned short* Ab = A + (size_t)bm0 * 512;
  const unsigned short* Bb = Bt + ((size_t)bb * 4096 + bn0) * 512;

  f32x4 acc[4][4];
#pragma unroll
  for (int m = 0; m < 4; ++m)
#pragma unroll
    for (int n = 0; n < 4; ++n) acc[m][n] = f32x4{0.f, 0.f, 0.f, 0.f};

#pragma unroll 1
  for (int kt = 0; kt < 8; ++kt) {
#pragma unroll
    for (int p = 0; p < 4; ++p) {
      int s = p * 256 + t;
      int row = s >> 3;
      int csg = (s & 7) ^ (row & 7);
      g2l16(Ab + (size_t)row * 512 + kt * 64 + csg * 8,
            &lds[(p * 256 + (t & ~63)) * 16]);
    }
#pragma unroll
    for (int p = 0; p < 4; ++p) {
      int s = p * 256 + t;
      int row = s >> 3;
      int csg = (s & 7) ^ (row & 7);
      g2l16(Bb + (size_t)row * 512 + kt * 64 + csg * 8,
            &lds[16384 + (p * 256 + (t & ~63)) * 16]);
    }
    __syncthreads();
#pragma unroll
    for (int kk = 0; kk < 2; ++kk) {
      short8 af[4], bfr[4];
#pragma unroll
      for (int m = 0; m < 4; ++m) {
        int row = wr * 64 + m * 16 + ln;
        int cs = (kk * 4 + g) ^ (row & 7);
        af[m] = *(const short8*)&lds[row * 128 + cs * 16];
      }
#pragma unroll
      for (int n = 0; n < 4; ++n) {
        int row = wc * 64 + n * 16 + ln;
        int cs = (kk * 4 + g) ^ (row & 7);
        bfr[n] = *(const short8*)&lds[16384 + row * 128 + cs * 16];
      }
      __builtin_amdgcn_s_setprio(1);
#pragma unroll
      for (int m = 0; m < 4; ++m)
#pragma unroll
        for (int n = 0; n < 4; ++n)
          acc[m][n] = __builtin_amdgcn_mfma_f32_16x16x32_bf16(af[m], bfr[n], acc[m][n], 0, 0, 0);
      __builtin_amdgcn_s_setprio(0);
    }
    __syncthreads();
  }

  if (MODE == 0) {
#pragma unroll
    for (int m = 0; m < 4; ++m)
#pragma unroll
      for (int n = 0; n < 4; ++n)
#pragma unroll
        for (int r = 0; r < 4; ++r) {
          int ol = wr * 64 + m * 16 + g * 4 + r;
          int jl = wc * 64 + n * 16 + ln;
          int o = bm0 + ol, j = bn0 + jl;
          float v = acc[m][n][r] + bias[o];
          unsigned short bv = f2bf(v);
          if ((o % 192) >= 128) {  // V rows only, j bit-permuted within 64-blocks
            int jp = (j & ~63) | (j & 32) | ((j & 0xC) << 1) | ((j & 16) >> 2) | (j & 3);
            outA[((size_t)bb * 1536 + o) * 4096 + jp] = bv;
          }
          *(unsigned short*)&lds[jl * 272 + ol * 2] = bv;
        }
    __syncthreads();
#pragma unroll
    for (int p = 0; p < 8; ++p) {
      int s = p * 256 + t;
      int jl = s >> 4, cs = s & 15;
      int oo = bm0 + cs * 8;
      if ((oo % 192) < 128) {  // Q,K rows only
        short8 v = *(const short8*)&lds[jl * 272 + cs * 16];
        *(short8*)&outT[((size_t)bb * 4096 + bn0 + jl) * 1536 + oo] = v;
      }
    }
  } else {
#pragma unroll
    for (int m = 0; m < 4; ++m)
#pragma unroll
      for (int n = 0; n < 4; ++n)
#pragma unroll
        for (int r = 0; r < 4; ++r) {
          int o = bm0 + wr * 64 + m * 16 + g * 4 + r;
          int j = bn0 + wc * 64 + n * 16 + ln;
          size_t idx = ((size_t)bb * 512 + o) * 4096 + j;
          outF[idx] = acc[m][n][r] + bias[o] + bf2f(resid[idx]);
        }
  }
}

// ---------------- Flash attention v11: 4 waves x 64 q-rows (best measured config) ----------------
// grid (32 q-tiles of 128, 8 heads, 2 batch) = 512 blocks, 256 threads (4 waves).
// Wave (qw=wid>>1, jw=wid&1) owns q-subtile qw*64 (64 rows, qt=0..3) x j-slice
// jw*32. Session evidence: wall time == serial sum of matrix+trans+VALU pipes,
// invariant across occupancy (2x), LDS traffic (4x), barrier count (2x), three
// scheduling restructures, and a 32x32-MFMA port (bank conflicts). This config
// produced the best total (124.9 us). Zero LDS bank conflicts.
__global__ __launch_bounds__(256, 2) void k_attn(const unsigned short* __restrict__ qkv,
                                                 const unsigned short* __restrict__ qkvT,
                                                 unsigned short* __restrict__ aT) {
  __shared__ char lds[49152];  // K: cur*8192, V: 24576 + cur*8192
  const int t = threadIdx.x, lane = t & 63;
  const int g = lane >> 4, ln = lane & 15;
  const int wid = t >> 6;   // 0..3
  const int qw = wid >> 1;  // q-subtile 0..1 (64 rows each)
  const int jw = wid & 1;   // j-slice 0..1
  const int h = blockIdx.y, bb = blockIdx.z;
  const int q0 = blockIdx.x * 128 + qw * 64;

  // K fragment addrs [kk_d][jf]; V fragment addrs [df] (slice jw)
  int kaddr[2][2], vaddr[4];
#pragma unroll
  for (int kk = 0; kk < 2; ++kk)
#pragma unroll
    for (int jf = 0; jf < 2; ++jf) {
      int row = jw * 32 + jf * 16 + ln;
      kaddr[kk][jf] = row * 128 + (((kk * 4 + g) ^ (row & 7)) << 4);
    }
#pragma unroll
  for (int df = 0; df < 4; ++df) {
    int row = df * 16 + ln;
    vaddr[df] = 24576 + row * 128 + (((jw * 4 + g) ^ (row & 7)) << 4);
  }

  // staging: 256 threads x 2 segments cover each 8KB tile (K and V)
  const unsigned short* kS[2];
  const unsigned short* vS[2];
  int ldst[2];
#pragma unroll
  for (int p = 0; p < 2; ++p) {
    int s = p * 256 + t;
    int row = s >> 3, csg = (s & 7) ^ (row & 7);
    kS[p] = qkvT + ((size_t)bb * 4096 + row) * 1536 + 192 * h + 64 + csg * 8;
    vS[p] = qkv + ((size_t)bb * 1536 + 192 * h + 128 + row) * 4096 + csg * 8;
    ldst[p] = (p * 256 + (t & ~63)) * 16;  // wave-uniform base; g2l16 adds lane*16
  }

  // Q fragments [qt][kk_d], pre-scaled by 0.125*log2(e)
  short8 qf[4][2];
#pragma unroll
  for (int qt = 0; qt < 4; ++qt)
#pragma unroll
    for (int kk = 0; kk < 2; ++kk) {
      short8 v = *(const short8*)(qkvT + ((size_t)bb * 4096 + q0 + qt * 16 + ln) * 1536 +
                                  192 * h + kk * 32 + g * 8);
#pragma unroll
      for (int e = 0; e < 8; ++e) {
        float f = bf2f((unsigned short)v[e]) * QSCALE;
        v[e] = (short)f2bf(f);
      }
      qf[qt][kk] = v;
    }

  // all-ones bf16 B fragment for the row-sum MFMA
  const short8 onesb = mk8(0x3F803F80u, 0x3F803F80u, 0x3F803F80u, 0x3F803F80u);

  f32x4 acc[4][4];
  f32x4 lacc[4];
#pragma unroll
  for (int qt = 0; qt < 4; ++qt) {
#pragma unroll
    for (int df = 0; df < 4; ++df) acc[qt][df] = f32x4{0.f, 0.f, 0.f, 0.f};
    lacc[qt] = f32x4{0.f, 0.f, 0.f, 0.f};
  }

  // prologue: stage tiles 0 (buf0) and 1 (buf1): 8 loads
#pragma unroll
  for (int jt = 0; jt < 2; ++jt) {
#pragma unroll
    for (int p = 0; p < 2; ++p) {
      g2l16(kS[p], &lds[jt * 8192 + ldst[p]]);
      g2l16(vS[p], &lds[24576 + jt * 8192 + ldst[p]]);
      kS[p] += 64 * 1536;
      vS[p] += 64;
    }
  }

  // ---- main loop: QK(slice) -> exp -> pack -> PV(slice), all in-iteration ----
#pragma unroll 3
  for (int jt = 0; jt < 64; ++jt) {
    const int cur = jt % 3;
    const char* Kc = &lds[cur * 8192];  // vaddr carries the 24576 V base
    if (jt < 63) {
      asm volatile("s_waitcnt vmcnt(4) lgkmcnt(0)" ::: "memory");
    } else {
      asm volatile("s_waitcnt vmcnt(0) lgkmcnt(0)" ::: "memory");
    }
    __builtin_amdgcn_s_barrier();
    __builtin_amdgcn_sched_barrier(0);

    // stage tile jt+2 into buf (jt+2)%3 (safe: all waves passed barrier jt
    // with lgkmcnt(0), so no wave still reads that buffer)
    if (jt < 62) {
      int nb = (jt + 2) % 3;
#pragma unroll
      for (int p = 0; p < 2; ++p) {
        g2l16(kS[p], &lds[nb * 8192 + ldst[p]]);
        g2l16(vS[p], &lds[24576 + nb * 8192 + ldst[p]]);
        kS[p] += 64 * 1536;
        vS[p] += 64;
      }
    }

    // K slice fragments (4 b128, conflict-free)
    short8 kf[2][2];
#pragma unroll
    for (int kk = 0; kk < 2; ++kk)
#pragma unroll
      for (int jf = 0; jf < 2; ++jf) kf[kk][jf] = *(const short8*)(Kc + kaddr[kk][jf]);

    // QK^T over the slice: w[qt][jf], 16 MFMA, C folded to const zero
    const f32x4 zf = f32x4{0.f, 0.f, 0.f, 0.f};
    f32x4 w[4][2];
    __builtin_amdgcn_s_setprio(1);
#pragma unroll
    for (int qt = 0; qt < 4; ++qt)
#pragma unroll
      for (int jf = 0; jf < 2; ++jf)
        w[qt][jf] = __builtin_amdgcn_mfma_f32_16x16x32_bf16(kf[0][jf], qf[qt][0], zf, 0, 0, 0);
#pragma unroll
    for (int qt = 0; qt < 4; ++qt)
#pragma unroll
      for (int jf = 0; jf < 2; ++jf)
        w[qt][jf] = __builtin_amdgcn_mfma_f32_16x16x32_bf16(kf[1][jf], qf[qt][1], w[qt][jf], 0, 0, 0);
    __builtin_amdgcn_s_setprio(0);

    // V slice fragments (4 b128) -- issued before exp so ds latency hides there
    short8 vf[4];
#pragma unroll
    for (int df = 0; df < 4; ++df) vf[df] = *(const short8*)(Kc + vaddr[df]);

    // p = exp2(w), 32 trans ops
#pragma unroll
    for (int qt = 0; qt < 4; ++qt)
#pragma unroll
      for (int jf = 0; jf < 2; ++jf)
#pragma unroll
        for (int r = 0; r < 4; ++r) w[qt][jf][r] = __builtin_amdgcn_exp2f(w[qt][jf][r]);

    // pack to bf16 A-fragments (K=32 contraction block = this wave's j-slice)
    short8 pf[4];
#pragma unroll
    for (int qt = 0; qt < 4; ++qt)
      pf[qt] = mk8(cvtpk(w[qt][0][0], w[qt][0][1]),
                   cvtpk(w[qt][0][2], w[qt][0][3]),
                   cvtpk(w[qt][1][0], w[qt][1][1]),
                   cvtpk(w[qt][1][2], w[qt][1][3]));

    // PV over the slice + ones row-sum, 20 MFMA
    __builtin_amdgcn_s_setprio(1);
#pragma unroll
    for (int qt = 0; qt < 4; ++qt) {
#pragma unroll
      for (int df = 0; df < 4; ++df)
        acc[qt][df] = __builtin_amdgcn_mfma_f32_16x16x32_bf16(pf[qt], vf[df], acc[qt][df], 0, 0, 0);
      lacc[qt] = __builtin_amdgcn_mfma_f32_16x16x32_bf16(pf[qt], onesb, lacc[qt], 0, 0, 0);
    }
    __builtin_amdgcn_s_setprio(0);
  }

  // ---- epilogue: combine jw partials via LDS (reuse K/V buffers), then write ----
  __syncthreads();
  float* cb = (float*)lds;
  const int cbase = qw * 5120;  // floats; 20 KB per qw, 40 KB total
  if (jw == 1) {
#pragma unroll
    for (int qt = 0; qt < 4; ++qt) {
#pragma unroll
      for (int df = 0; df < 4; ++df)
        *(f32x4*)&cb[cbase + ((qt * 4 + df) * 64 + lane) * 4] = acc[qt][df];
      *(f32x4*)&cb[cbase + 4096 + (qt * 64 + lane) * 4] = lacc[qt];
    }
  }
  __syncthreads();
  if (jw == 0) {
#pragma unroll
    for (int qt = 0; qt < 4; ++qt) {
#pragma unroll
      for (int df = 0; df < 4; ++df)
        acc[qt][df] += *(const f32x4*)&cb[cbase + ((qt * 4 + df) * 64 + lane) * 4];
      lacc[qt] += *(const f32x4*)&cb[cbase + 4096 + (qt * 64 + lane) * 4];
    }
#pragma unroll
    for (int qt = 0; qt < 4; ++qt)
#pragma unroll
      for (int r = 0; r < 4; ++r) {
        float inv = 1.f / lacc[qt][r];
        int row = q0 + qt * 16 + g * 4 + r;
#pragma unroll
        for (int df = 0; df < 4; ++df)
          aT[((size_t)bb * 4096 + row) * 512 + h * 64 + df * 16 + ln] =
              f2bf(acc[qt][df][r] * inv);
      }
  }
}

// ---------------- launcher ----------------
extern "C" void kernel_launch(void* const* d_in, const int* in_sizes, int n_in,
                              void* d_out, int out_size, void* d_ws, size_t ws_size,
                              hipStream_t stream) {
  const float* x     = (const float*)d_in[0];
  const float* gnw   = (const float*)d_in[1];
  const float* gnb   = (const float*)d_in[2];
  const float* qkvw  = (const float*)d_in[3];
  const float* qkvb  = (const float*)d_in[4];
  const float* projw = (const float*)d_in[5];
  const float* projb = (const float*)d_in[6];
  float* out = (float*)d_out;
  char* ws = (char*)d_ws;

  const size_t OFF_WQ   = 0;
  const size_t OFF_WP   = 1572864;
  const size_t OFF_XN   = 2097152;
  const size_t OFF_XNT  = 10485760;
  const size_t OFF_QKV  = 18874368;
  const size_t OFF_QKVT = 44040192;
  const size_t OFF_AT   = 69206016;
  const size_t OFF_PART = 77594624;
  const size_t OFF_STAT = 77602816;

  unsigned short* wq   = (unsigned short*)(ws + OFF_WQ);
  unsigned short* wp   = (unsigned short*)(ws + OFF_WP);
  unsigned short* xn   = (unsigned short*)(ws + OFF_XN);
  unsigned short* xnT  = (unsigned short*)(ws + OFF_XNT);
  unsigned short* qkv  = (unsigned short*)(ws + OFF_QKV);
  unsigned short* qkvT = (unsigned short*)(ws + OFF_QKVT);
  unsigned short* aT   = (unsigned short*)(ws + OFF_AT);
  float* part  = (float*)(ws + OFF_PART);
  float* stats = (float*)(ws + OFF_STAT);

  k_wgn<<<dim3(2048), dim3(256), 0, stream>>>(qkvw, projw, wq, wp, x, part);
  k_gnfin<<<dim3(1), dim3(64), 0, stream>>>(part, stats);
  k_gnnorm<<<dim3(64, 8, 2), dim3(256), 0, stream>>>(x, gnw, gnb, stats, xn, xnT);
  k_gemm<0><<<dim3(32, 12, 2), dim3(256), 0, stream>>>(wq, xnT, qkvb, qkv, qkvT, nullptr, nullptr, 1536);
  k_attn<<<dim3(32, 8, 2), dim3(256), 0, stream>>>(qkv, qkvT, aT);
  k_gemm<1><<<dim3(32, 4, 2), dim3(256), 0, stream>>>(wp, aT, projb, nullptr, nullptr, xn, out, 512);
}